// Round 10
// baseline (143.556 us; speedup 1.0000x reference)
//
#include <hip/hip_runtime.h>

typedef __attribute__((ext_vector_type(8))) short short8;
typedef __attribute__((ext_vector_type(4))) float floatx4;
typedef __attribute__((ext_vector_type(4))) unsigned uintx4;

#define NTYPES    64
#define WT_STRIDE 5632   // ushorts per type in transposed weight array
#define WROWS     16     // sorted rows per window (= one MFMA tile)
#define NWIN      4      // windows per persistent wave
#define CPAD      16     // counter padding (ints) -> 64B
#define RSTRIDE   976    // padded LDS row stride bytes (61*16: 2-way banks = free)

__device__ __forceinline__ unsigned short f2bf(float f) {
    union { float f; unsigned u; } v; v.f = f;
    unsigned u = v.u;
    u += 0x7FFFu + ((u >> 16) & 1u);   // round-to-nearest-even
    return (unsigned short)(u >> 16);
}

__device__ __forceinline__ unsigned pk2(float lo, float hi) {
    unsigned r;
    asm("v_cvt_pk_bf16_f32 %0, %1, %2" : "=v"(r) : "v"(lo), "v"(hi));
    return r;
}

// ---- weight transpose (LDS-staged, bf16, scale folded) + partial histogram ----
__global__ __launch_bounds__(256) void wt_kernel(const float* __restrict__ W0,
                                                 const float* __restrict__ W1,
                                                 const float* __restrict__ W2,
                                                 const int* __restrict__ idx,
                                                 unsigned short* __restrict__ wt,
                                                 int* __restrict__ bh, int n) {
    __shared__ float ws0[4096];
    __shared__ float ws1[1024];
    __shared__ float ws2[256];
    __shared__ int hc[NTYPES];
    const int t = blockIdx.x, tid = threadIdx.x;
    if (tid < NTYPES) hc[tid] = 0;
    const float4* s0 = (const float4*)(W0 + (size_t)t * 4096);
#pragma unroll
    for (int j = 0; j < 4; ++j) ((float4*)ws0)[j * 256 + tid] = s0[j * 256 + tid];
    ((float4*)ws1)[tid] = ((const float4*)(W1 + (size_t)t * 1024))[tid];
    if (tid < 64) ((float4*)ws2)[tid] = ((const float4*)(W2 + (size_t)t * 256))[tid];
    __syncthreads();
    const int per = (n + NTYPES - 1) / NTYPES;
    for (int e = tid; e < per; e += 256) {
        int g = t * per + e;
        if (g < n) atomicAdd(&hc[idx[g]], 1);
    }
    unsigned short* dst = wt + (size_t)t * WT_STRIDE;
    for (int e = tid; e < 4096; e += 256) {
        int f = e >> 9, rem = e & 511, rr = rem >> 5, k2 = rem & 31;
        int i = (f & 1) * 32 + k2, o = (f >> 1) * 16 + rr;
        dst[e] = f2bf(ws0[i * 64 + o] * 0.125f);
    }
    for (int e = tid; e < 1024; e += 256) {
        int h = e >> 9, rem = e & 511, rr = rem >> 5, k = rem & 31;
        dst[4096 + e] = f2bf(ws1[k * 32 + h * 16 + rr] * 0.17677669529663687f);
    }
    for (int e = tid; e < 512; e += 256) {
        int rr = e >> 5, k = e & 31;
        dst[5120 + e] = (k < 16) ? f2bf(ws2[k * 16 + rr] * 0.25f) : (unsigned short)0;
    }
    __syncthreads();
    if (tid < NTYPES) bh[t * NTYPES + tid] = hc[tid];
}

// ---- sort pass 2: sum 64 partial hists, one-wave exclusive scan -> cursors ----
__global__ __launch_bounds__(64) void base_kernel(const int* __restrict__ bh,
                                                  int* __restrict__ gcur) {
    const int t = threadIdx.x;
    int v = 0;
#pragma unroll
    for (int b = 0; b < NTYPES; ++b) v += bh[b * NTYPES + t];
    int s = v;
#pragma unroll
    for (int o = 1; o < 64; o <<= 1) {
        int u = __shfl_up(s, o);
        if (t >= o) s += u;
    }
    gcur[t * CPAD] = s - v;
}

// ---- sort pass 3: block reserves a chunk per type, writes packed node|ty<<24 ----
__global__ __launch_bounds__(256) void scatter_kernel(const int* __restrict__ idx,
                                                      int* __restrict__ gcur,
                                                      int* __restrict__ psort, int n) {
    __shared__ int c[NTYPES], off[NTYPES], cur[NTYPES];
    const int tid = threadIdx.x, g = blockIdx.x * 256 + tid;
    if (tid < NTYPES) { c[tid] = 0; cur[tid] = 0; }
    __syncthreads();
    int ty = -1;
    if (g < n) { ty = idx[g]; atomicAdd(&c[ty], 1); }
    __syncthreads();
    if (tid < NTYPES && c[tid]) off[tid] = atomicAdd(&gcur[tid * CPAD], c[tid]);
    __syncthreads();
    if (g < n) {
        int rk = atomicAdd(&cur[ty], 1);
        psort[off[ty] + rk] = g | (ty << 24);
    }
}

// weight-fragment load cluster (11 x b128 from one type's table)
#define LOAD_FRAGS(WB) do {                                         \
    const unsigned short* _wp = (WB) + r * 32 + q4 * 8;             \
    wa0 = *(const short8*)(_wp);                                    \
    wa1 = *(const short8*)(_wp + 512);                              \
    wa2 = *(const short8*)(_wp + 1024);                             \
    wa3 = *(const short8*)(_wp + 1536);                             \
    wa4 = *(const short8*)(_wp + 2048);                             \
    wa5 = *(const short8*)(_wp + 2560);                             \
    wa6 = *(const short8*)(_wp + 3072);                             \
    wa7 = *(const short8*)(_wp + 3584);                             \
    wc0 = *(const short8*)(_wp + 4096);                             \
    wc1 = *(const short8*)(_wp + 4608);                             \
    wc2 = *(const short8*)(_wp + 5120);                             \
} while (0)

// stage one 16-row window (win) into LDS buffer (buf): 16 async 1KB DMAs
#define STAGE(buf, win) do {                                                     \
    _Pragma("unroll")                                                            \
    for (int k = 0; k < 16; ++k) {                                               \
        int L = k * 1024 + ln * 16;                                              \
        int row = (int)(((unsigned)(L >> 4) * 1075u) >> 16);                     \
        int col = L - row * RSTRIDE;                                             \
        int node = __shfl(pe, (win) * 16 + min(row, 15)) & 0xFFFFFF;             \
        int colc = min(col, 944);                                                \
        const float* src = x + (size_t)node * 240 + (colc >> 2);                 \
        __builtin_amdgcn_global_load_lds(                                        \
            (const __attribute__((address_space(1))) void*)src,                  \
            (__attribute__((address_space(3))) void*)(xl[buf] + k * 1024),       \
            16, 0, 0);                                                           \
    }                                                                            \
} while (0)

// ---- main: persistent 1-wave blocks; 4 windows/wave; LDS double-buffer;
// ---- counted vmcnt(26) so next window's 16 DMAs stay in flight under compute.
// ---- All 15 stores/tile always issue (invalid lanes -> per-lane sink) so the
// ---- vmcnt arithmetic is deterministic.
__global__ __launch_bounds__(64) void main_kernel(
    const float* __restrict__ x,
    const int* __restrict__ psort,
    const unsigned short* __restrict__ wt,
    float* __restrict__ out, float* __restrict__ sink, int n)
{
    __shared__ __align__(16) unsigned char xl[2][16384];
    const int ln = threadIdx.x;
    const int r = ln & 15, q4 = ln >> 4;
    const int gbase = blockIdx.x * (WROWS * NWIN);
    if (gbase >= n) return;

    int pe = 0;
    if (gbase + ln < n) pe = psort[gbase + ln];   // one load covers 4 windows

    float* snk = sink + ln * 4;                   // per-lane garbage bin (16B)

    STAGE(0, 0);

#pragma unroll
    for (int t = 0; t < NWIN; ++t) {
        const int wb = gbase + t * WROWS;
        if (wb >= n) break;
        const int nv = min(WROWS, n - wb);
        const int buf = t & 1;

        if (t == 0) asm volatile("s_waitcnt vmcnt(0)" ::: "memory");
        else        asm volatile("s_waitcnt vmcnt(26)" ::: "memory");
        __builtin_amdgcn_sched_barrier(0);

        // ---- LDS -> f32 fragment sources (all 16B-aligned b128) ----
        const float4* xr = (const float4*)(xl[buf] + r * RSTRIDE);
        float4 f0a = xr[q4 * 2],     f0b = xr[q4 * 2 + 1];
        float4 f0c = xr[8 + q4 * 2], f0d = xr[9 + q4 * 2];
        float4 g0 = xr[16 + q4 * 6],     g1 = xr[16 + q4 * 6 + 1], g2 = xr[16 + q4 * 6 + 2];
        float4 g3 = xr[16 + q4 * 6 + 3], g4 = xr[16 + q4 * 6 + 4], g5 = xr[16 + q4 * 6 + 5];
        const int hb = 40 + (q4 & 1) * 10;
        float4 h0 = xr[hb],     h1 = xr[hb + 1], h2 = xr[hb + 2], h3 = xr[hb + 3];
        float4 h4 = xr[hb + 4], h5 = xr[hb + 5], h6 = xr[hb + 6], h7 = xr[hb + 7];
        float4 h8 = xr[hb + 8], h9 = xr[hb + 9];

        // prefetch next window while this one computes (other LDS buffer)
        if (t + 1 < NWIN && gbase + (t + 1) * WROWS < n) STAGE(buf ^ 1, t + 1);

        // segment structure of this window
        int ti  = __shfl(pe, t * 16 + r) >> 24;
        int tim = __shfl(pe, t * 16 + ((r > 0) ? (r - 1) : 0)) >> 24;
        bool bnd = (r == 0) || (ti != tim);
        unsigned m = (unsigned)(__ballot(bnd) & 0xFFFFull);
        const int ty0 = __shfl(pe, t * 16) >> 24;

        short8 wa0, wa1, wa2, wa3, wa4, wa5, wa6, wa7, wc0, wc1, wc2;
        LOAD_FRAGS(wt + (size_t)ty0 * WT_STRIDE);

        union frag { short8 s; uintx4 u; };
        frag bx0, bx1;
        bx0.u = uintx4{pk2(f0a.x, f0a.y), pk2(f0a.z, f0a.w),
                       pk2(f0b.x, f0b.y), pk2(f0b.z, f0b.w)};
        bx1.u = uintx4{pk2(f0c.x, f0c.y), pk2(f0c.z, f0c.w),
                       pk2(f0d.x, f0d.y), pk2(f0d.z, f0d.w)};
        const float G[24] = {g0.x, g0.y, g0.z, g0.w, g1.x, g1.y, g1.z, g1.w,
                             g2.x, g2.y, g2.z, g2.w, g3.x, g3.y, g3.z, g3.w,
                             g4.x, g4.y, g4.z, g4.w, g5.x, g5.y, g5.z, g5.w};
        frag b1d[3];
#pragma unroll
        for (int d = 0; d < 3; ++d)
            b1d[d].u = uintx4{pk2(G[d], G[3 + d]), pk2(G[6 + d], G[9 + d]),
                              pk2(G[12 + d], G[15 + d]), pk2(G[18 + d], G[21 + d])};
        const float H[40] = {h0.x, h0.y, h0.z, h0.w, h1.x, h1.y, h1.z, h1.w,
                             h2.x, h2.y, h2.z, h2.w, h3.x, h3.y, h3.z, h3.w,
                             h4.x, h4.y, h4.z, h4.w, h5.x, h5.y, h5.z, h5.w,
                             h6.x, h6.y, h6.z, h6.w, h7.x, h7.y, h7.z, h7.w,
                             h8.x, h8.y, h8.z, h8.w, h9.x, h9.y, h9.z, h9.w};
        frag b2d[5];
#pragma unroll
        for (int d = 0; d < 5; ++d)
            b2d[d].u = uintx4{pk2(H[d], H[5 + d]), pk2(H[10 + d], H[15 + d]),
                              pk2(H[20 + d], H[25 + d]), pk2(H[30 + d], H[35 + d])};

        const bool vrow = (r < nv);
        const int node_r = __shfl(pe, t * 16 + min(r, nv - 1)) & 0xFFFFFF;
        float* op = out + (size_t)node_r * 240;

        while (true) {
            const int slo = __builtin_ctz(m);
            const unsigned m2 = m & (m - 1u);
            const int shi = m2 ? __builtin_ctz(m2) : nv;
            const bool vst = vrow && (r >= slo) && (r < shi);
#define OST(p) ((floatx4*)(vst ? (float*)(p) : snk))

            // ---- irrep0: D[o=nt*16+q4*4+reg][node=r], K=64 ----
            {
                floatx4 ac;
                ac = floatx4{0.f, 0.f, 0.f, 0.f};
                ac = __builtin_amdgcn_mfma_f32_16x16x32_bf16(wa0, bx0.s, ac, 0, 0, 0);
                ac = __builtin_amdgcn_mfma_f32_16x16x32_bf16(wa1, bx1.s, ac, 0, 0, 0);
                *OST(op + q4 * 4) = ac;
                ac = floatx4{0.f, 0.f, 0.f, 0.f};
                ac = __builtin_amdgcn_mfma_f32_16x16x32_bf16(wa2, bx0.s, ac, 0, 0, 0);
                ac = __builtin_amdgcn_mfma_f32_16x16x32_bf16(wa3, bx1.s, ac, 0, 0, 0);
                *OST(op + 16 + q4 * 4) = ac;
                ac = floatx4{0.f, 0.f, 0.f, 0.f};
                ac = __builtin_amdgcn_mfma_f32_16x16x32_bf16(wa4, bx0.s, ac, 0, 0, 0);
                ac = __builtin_amdgcn_mfma_f32_16x16x32_bf16(wa5, bx1.s, ac, 0, 0, 0);
                *OST(op + 32 + q4 * 4) = ac;
                ac = floatx4{0.f, 0.f, 0.f, 0.f};
                ac = __builtin_amdgcn_mfma_f32_16x16x32_bf16(wa6, bx0.s, ac, 0, 0, 0);
                ac = __builtin_amdgcn_mfma_f32_16x16x32_bf16(wa7, bx1.s, ac, 0, 0, 0);
                *OST(op + 48 + q4 * 4) = ac;
            }

            // ---- irrep1: per d, 2 M-tiles; 12 consecutive floats as 3x float4 ----
            {
                floatx4 a1[2][3];
#pragma unroll
                for (int d = 0; d < 3; ++d) {
                    floatx4 z = {0.f, 0.f, 0.f, 0.f};
                    a1[0][d] = __builtin_amdgcn_mfma_f32_16x16x32_bf16(wc0, b1d[d].s, z, 0, 0, 0);
                    a1[1][d] = __builtin_amdgcn_mfma_f32_16x16x32_bf16(wc1, b1d[d].s, z, 0, 0, 0);
                }
#pragma unroll
                for (int h = 0; h < 2; ++h) {
                    float* o1 = op + 64 + (h * 16 + q4 * 4) * 3;
                    floatx4 v0 = {a1[h][0][0], a1[h][1][0], a1[h][2][0], a1[h][0][1]};
                    floatx4 v1 = {a1[h][1][1], a1[h][2][1], a1[h][0][2], a1[h][1][2]};
                    floatx4 v2 = {a1[h][2][2], a1[h][0][3], a1[h][1][3], a1[h][2][3]};
                    *OST(o1)     = v0;
                    *OST(o1 + 4) = v1;
                    *OST(o1 + 8) = v2;
                }
            }

            // ---- irrep2: per d, M=16 K=16 (w-side zero-padded); 5x float4 ----
            {
                floatx4 a2[5];
#pragma unroll
                for (int d = 0; d < 5; ++d) {
                    floatx4 z = {0.f, 0.f, 0.f, 0.f};
                    a2[d] = __builtin_amdgcn_mfma_f32_16x16x32_bf16(wc2, b2d[d].s, z, 0, 0, 0);
                }
                float* o2 = op + 160 + q4 * 20;
                floatx4 v0 = {a2[0][0], a2[1][0], a2[2][0], a2[3][0]};
                floatx4 v1 = {a2[4][0], a2[0][1], a2[1][1], a2[2][1]};
                floatx4 v2 = {a2[3][1], a2[4][1], a2[0][2], a2[1][2]};
                floatx4 v3 = {a2[2][2], a2[3][2], a2[4][2], a2[0][3]};
                floatx4 v4 = {a2[1][3], a2[2][3], a2[3][3], a2[4][3]};
                *OST(o2)      = v0;
                *OST(o2 + 4)  = v1;
                *OST(o2 + 8)  = v2;
                *OST(o2 + 12) = v3;
                *OST(o2 + 16) = v4;
            }
#undef OST
            m = m2;
            if (!m) break;
            const int tyn = __shfl(pe, t * 16 + __builtin_ctz(m)) >> 24;
            LOAD_FRAGS(wt + (size_t)tyn * WT_STRIDE);
        }
    }
}

extern "C" void kernel_launch(void* const* d_in, const int* in_sizes, int n_in,
                              void* d_out, int out_size, void* d_ws, size_t ws_size,
                              hipStream_t stream) {
    const float* x  = (const float*)d_in[0];
    const float* W0 = (const float*)d_in[1];
    const float* W1 = (const float*)d_in[2];
    const float* W2 = (const float*)d_in[3];
    const int*   idx = (const int*)d_in[4];
    float* out = (float*)d_out;
    const int n = in_sizes[4];                    // 65536 nodes
    const int nb = (n + 255) / 256;

    char* ws = (char*)d_ws;
    unsigned short* wt = (unsigned short*)ws;     // 720896 B
    size_t off = (size_t)NTYPES * WT_STRIDE * 2;
    int* psort = (int*)(ws + off); off += (size_t)n * 4;
    int* bh    = (int*)(ws + off); off += (size_t)NTYPES * NTYPES * 4;
    int* gcur  = (int*)(ws + off); off += (size_t)NTYPES * CPAD * 4;
    float* sink = (float*)(ws + off);             // 1 KB garbage bin

    wt_kernel     <<<NTYPES, 256, 0, stream>>>(W0, W1, W2, idx, wt, bh, n);
    base_kernel   <<<1, 64, 0, stream>>>(bh, gcur);
    scatter_kernel<<<nb, 256, 0, stream>>>(idx, gcur, psort, n);
    const int rows_pb = WROWS * NWIN;
    main_kernel   <<<(n + rows_pb - 1) / rows_pb, 64, 0, stream>>>(x, psort, wt, out, sink, n);
}